// Round 2
// baseline (4282.900 us; speedup 1.0000x reference)
//
#include <hip/hip_runtime.h>
#include <math.h>

#define S_LEN 200
#define BATCH 64
#define HID   512
#define NTAG  22
#define TCH   25              // time-chunk for gates_x staging
#define MC    (TCH*BATCH)     // 1600 rows per chunk GEMM

typedef unsigned short u16;
typedef unsigned int   u32;

__device__ __forceinline__ float bf2f(u16 u){
  union { u32 ui; float f; } v; v.ui = ((u32)u) << 16; return v.f;
}

// ---------------------------------------------------------------------------
// Detect whether float inputs are bf16 (packed u16) or fp32.
__global__ void k_detect(const u32* __restrict__ w, int* __restrict__ flag){
  __shared__ int cnt;
  if (threadIdx.x == 0) cnt = 0;
  __syncthreads();
  int hits = 0;
  for (int i = threadIdx.x; i < 16384; i += 256){
    u32 e = (w[i] & 0x7F80u);
    if (e >= 0x3800u && e <= 0x4080u) hits++;
  }
  atomicAdd(&cnt, hits);
  __syncthreads();
  if (threadIdx.x == 0) *flag = (cnt > 8192) ? 1 : 0;
}

__global__ void k_cvt_f(const void* __restrict__ src, float* __restrict__ dst,
                        int n, const int* __restrict__ flag){
  int i = blockIdx.x*blockDim.x + threadIdx.x;
  if (i >= n) return;
  if (*flag) dst[i] = bf2f(((const u16*)src)[i]);
  else       dst[i] = ((const float*)src)[i];
}

__global__ void k_zero(float* __restrict__ p, int n){
  int i = blockIdx.x*blockDim.x + threadIdx.x;
  if (i < n) p[i] = 0.f;
}

// ---------------------------------------------------------------------------
// Build fwd_in/bwd_in [S][B][256] fp32: char embedding + masked gaz mean,
// with reverse_padded_sequence applied for the backward direction.
__global__ __launch_bounds__(128)
void k_build(const int* __restrict__ ci, const int* __restrict__ lengths,
             const int* __restrict__ gid, const int* __restrict__ gm,
             const int* __restrict__ rgid, const int* __restrict__ rgm,
             const void* __restrict__ ctab, const void* __restrict__ gtab,
             const int* __restrict__ flag,
             float* __restrict__ fin, float* __restrict__ bin)
{
  int bs = blockIdx.x;              // b*S_LEN + s
  int b = bs / S_LEN, s = bs % S_LEN;
  int d = threadIdx.x;              // 0..127
  int isbf = *flag;
  int len = lengths[b];
  int sb = (s < len) ? (len - 1 - s) : s;
  size_t orow = ((size_t)s*BATCH + b)*256;

  // forward
  {
    int cid = ci[bs];
    float cv = isbf ? bf2f(((const u16*)ctab)[(size_t)cid*128 + d])
                    : ((const float*)ctab)[(size_t)cid*128 + d];
    fin[orow + d] = cv;
    const int* gg = gid + (size_t)bs*8;
    const int* mm = gm  + (size_t)bs*8;
    float sum = 0.f, cntf = 0.f;
    for (int g = 0; g < 8; ++g){
      float m = (float)mm[g];
      int gw = gg[g];
      float gv = isbf ? bf2f(((const u16*)gtab)[(size_t)gw*128 + d])
                      : ((const float*)gtab)[(size_t)gw*128 + d];
      sum += m * gv; cntf += m;
    }
    fin[orow + 128 + d] = sum / fmaxf(cntf, 1.f);
  }
  // backward (gather position sb)
  {
    int bsr = b*S_LEN + sb;
    int cid = ci[bsr];
    float cv = isbf ? bf2f(((const u16*)ctab)[(size_t)cid*128 + d])
                    : ((const float*)ctab)[(size_t)cid*128 + d];
    bin[orow + d] = cv;
    const int* gg = rgid + (size_t)bsr*8;
    const int* mm = rgm  + (size_t)bsr*8;
    float sum = 0.f, cntf = 0.f;
    for (int g = 0; g < 8; ++g){
      float m = (float)mm[g];
      int gw = gg[g];
      float gv = isbf ? bf2f(((const u16*)gtab)[(size_t)gw*128 + d])
                      : ((const float*)gtab)[(size_t)gw*128 + d];
      sum += m * gv; cntf += m;
    }
    bin[orow + 128 + d] = sum / fmaxf(cntf, 1.f);
  }
}

// ---------------------------------------------------------------------------
// Chunked gates_x GEMM. For time chunk starting at t0:
//   A[m][k], m = tc*64+b (rows t0*64 .. t0*64+1599 of fin/bin), k<256
//   W[n][k], n < 2048
//   C[dir][n][m] = A.W^T + bias  (TRANSPOSED store so k_step batch reads coalesce)
__global__ __launch_bounds__(256)
void k_gemm_ih(const float* __restrict__ Af, const float* __restrict__ Ab,
               const float* __restrict__ wih,   // [2][2048][256]
               const float* __restrict__ bias,  // [2][2048]
               float* __restrict__ gxc,         // [2][2048][MC]
               int t0)
{
  const int dir = blockIdx.z;
  const float* A = (dir ? Ab : Af) + (size_t)t0*BATCH*256;
  const float* W = wih + (size_t)dir*2048*256;
  const float* bi = bias + (size_t)dir*2048;
  float* C = gxc + (size_t)dir*2048*MC;
  const int m0 = blockIdx.y * 64;
  const int n0 = blockIdx.x * 64;
  const int tid = threadIdx.x;
  __shared__ float As[32][64];
  __shared__ float Ws[32][64];
  const int lr = tid >> 2;       // 0..63
  const int kq = (tid & 3) * 8;  // 0,8,16,24
  const int tx = tid & 15;
  const int ty = tid >> 4;
  float acc[4][4] = {};

  for (int k0 = 0; k0 < 256; k0 += 32){
    float4 a0 = *(const float4*)(A + (size_t)(m0+lr)*256 + k0 + kq);
    float4 a1 = *(const float4*)(A + (size_t)(m0+lr)*256 + k0 + kq + 4);
    float4 w0 = *(const float4*)(W + (size_t)(n0+lr)*256 + k0 + kq);
    float4 w1 = *(const float4*)(W + (size_t)(n0+lr)*256 + k0 + kq + 4);
    As[kq+0][lr]=a0.x; As[kq+1][lr]=a0.y; As[kq+2][lr]=a0.z; As[kq+3][lr]=a0.w;
    As[kq+4][lr]=a1.x; As[kq+5][lr]=a1.y; As[kq+6][lr]=a1.z; As[kq+7][lr]=a1.w;
    Ws[kq+0][lr]=w0.x; Ws[kq+1][lr]=w0.y; Ws[kq+2][lr]=w0.z; Ws[kq+3][lr]=w0.w;
    Ws[kq+4][lr]=w1.x; Ws[kq+5][lr]=w1.y; Ws[kq+6][lr]=w1.z; Ws[kq+7][lr]=w1.w;
    __syncthreads();
    #pragma unroll 8
    for (int kk = 0; kk < 32; ++kk){
      float4 av = *(const float4*)(&As[kk][ty*4]);
      float4 wv = *(const float4*)(&Ws[kk][tx*4]);
      acc[0][0]+=av.x*wv.x; acc[0][1]+=av.x*wv.y; acc[0][2]+=av.x*wv.z; acc[0][3]+=av.x*wv.w;
      acc[1][0]+=av.y*wv.x; acc[1][1]+=av.y*wv.y; acc[1][2]+=av.y*wv.z; acc[1][3]+=av.y*wv.w;
      acc[2][0]+=av.z*wv.x; acc[2][1]+=av.z*wv.y; acc[2][2]+=av.z*wv.z; acc[2][3]+=av.z*wv.w;
      acc[3][0]+=av.w*wv.x; acc[3][1]+=av.w*wv.y; acc[3][2]+=av.w*wv.z; acc[3][3]+=av.w*wv.w;
    }
    __syncthreads();
  }

  #pragma unroll
  for (int j = 0; j < 4; ++j){
    float bj = bi[n0 + tx*4 + j];
    float4 o = make_float4(acc[0][j]+bj, acc[1][j]+bj, acc[2][j]+bj, acc[3][j]+bj);
    *(float4*)(C + (size_t)(n0 + tx*4 + j)*MC + m0 + ty*4) = o;
  }
}

// ---------------------------------------------------------------------------
// One LSTM time step for both directions. Grid (128 slices, 2 dirs), 256 thr.
__global__ __launch_bounds__(256)
void k_step(const float* __restrict__ whh,    // [2][2048][512] fp32
            const float* __restrict__ gxc,    // [2][2048][MC] (chunk)
            float* __restrict__ hbuf,         // [2][2][512][64]
            float* __restrict__ cbuf,         // [2][512][64]
            float* __restrict__ hseq,         // [2][200][512][64]
            int t, int tc)
{
  const int dir = blockIdx.y;
  const int slice = blockIdx.x;        // 0..127
  const int tid = threadIdx.x;
  const int b = tid & 63;
  const int r = tid >> 6;              // wave index 0..3
  const int row = slice*4 + r;

  __shared__ float hl[64*132];

  const float* hprev = hbuf + (size_t)(dir*2 + (t&1))*HID*BATCH;
  float* hnext       = hbuf + (size_t)(dir*2 + ((t+1)&1))*HID*BATCH;

  int urow = __builtin_amdgcn_readfirstlane(row);
  const float* wb0 = whh + (size_t)dir*2048*512;
  const float* w_i = wb0 + (size_t)(   0 + urow)*512;
  const float* w_f = wb0 + (size_t)( 512 + urow)*512;
  const float* w_g = wb0 + (size_t)(1024 + urow)*512;
  const float* w_o = wb0 + (size_t)(1536 + urow)*512;

  float ai=0.f, af=0.f, ag=0.f, ao=0.f;

  for (int ch = 0; ch < 4; ++ch){
    const int k0 = ch*128;
    const float4* src = (const float4*)(hprev + (size_t)k0*BATCH);
    const int lb = tid & 15;
    const int lk = tid >> 4;
    #pragma unroll
    for (int half = 0; half < 2; ++half){
      const int kqv = lk*4 + half*64;
      float4 g0 = src[(kqv+0)*16 + lb];
      float4 g1 = src[(kqv+1)*16 + lb];
      float4 g2 = src[(kqv+2)*16 + lb];
      float4 g3 = src[(kqv+3)*16 + lb];
      const int b0 = lb*4;
      *(float4*)(hl + (size_t)(b0+0)*132 + kqv) = make_float4(g0.x,g1.x,g2.x,g3.x);
      *(float4*)(hl + (size_t)(b0+1)*132 + kqv) = make_float4(g0.y,g1.y,g2.y,g3.y);
      *(float4*)(hl + (size_t)(b0+2)*132 + kqv) = make_float4(g0.z,g1.z,g2.z,g3.z);
      *(float4*)(hl + (size_t)(b0+3)*132 + kqv) = make_float4(g0.w,g1.w,g2.w,g3.w);
    }
    __syncthreads();
    const float* hcol = hl + (size_t)b*132;
    #pragma unroll 8
    for (int k = 0; k < 128; k += 4){
      float4 h4 = *(const float4*)(hcol + k);
      float4 wi = *(const float4*)(w_i + k0 + k);
      float4 wf = *(const float4*)(w_f + k0 + k);
      float4 wg = *(const float4*)(w_g + k0 + k);
      float4 wo = *(const float4*)(w_o + k0 + k);
      ai += wi.x*h4.x + wi.y*h4.y + wi.z*h4.z + wi.w*h4.w;
      af += wf.x*h4.x + wf.y*h4.y + wf.z*h4.z + wf.w*h4.w;
      ag += wg.x*h4.x + wg.y*h4.y + wg.z*h4.z + wg.w*h4.w;
      ao += wo.x*h4.x + wo.y*h4.y + wo.z*h4.z + wo.w*h4.w;
    }
    __syncthreads();
  }

  // coalesced gate reads: [dir][gate*512+row][tc*64+b]
  const float* gxb = gxc + (size_t)dir*2048*MC + (size_t)tc*BATCH + b;
  float gi = ai + gxb[(size_t)(   0 + row)*MC];
  float gf = af + gxb[(size_t)( 512 + row)*MC];
  float gg = ag + gxb[(size_t)(1024 + row)*MC];
  float go = ao + gxb[(size_t)(1536 + row)*MC];
  float si = 1.f/(1.f+expf(-gi));
  float sf = 1.f/(1.f+expf(-gf));
  float so = 1.f/(1.f+expf(-go));
  size_t ci_ = ((size_t)dir*HID + row)*BATCH + b;
  float c = cbuf[ci_];
  c = sf*c + si*tanhf(gg);
  float h = so*tanhf(c);
  cbuf[ci_] = c;
  hnext[(size_t)row*BATCH + b] = h;
  hseq[(((size_t)dir*S_LEN + t)*HID + row)*BATCH + b] = h;
}

// ---------------------------------------------------------------------------
__global__ __launch_bounds__(64)
void k_outproj(const float* __restrict__ hseq, const int* __restrict__ lengths,
               const float* __restrict__ wout,  // [1024][22]
               const float* __restrict__ bout,  // [22]
               float* __restrict__ emis)        // [64][200][22]
{
  int bs = blockIdx.x;
  int b = bs / S_LEN, s = bs % S_LEN;
  int len = lengths[b];
  int sb = (s < len) ? (len - 1 - s) : s;
  __shared__ float hcol[1024];
  int l = threadIdx.x;
  const float* hf = hseq + ((size_t)(0*S_LEN + s )*HID)*BATCH + b;
  const float* hb = hseq + ((size_t)(1*S_LEN + sb)*HID)*BATCH + b;
  for (int k = l; k < 512; k += 64){
    hcol[k]       = hf[(size_t)k*BATCH];
    hcol[512 + k] = hb[(size_t)k*BATCH];
  }
  __syncthreads();
  if (l < NTAG){
    float acc = bout[l];
    for (int k = 0; k < 1024; ++k) acc += hcol[k] * wout[k*NTAG + l];
    emis[(size_t)bs*NTAG + l] = acc;
  }
}

// ---------------------------------------------------------------------------
// CRF Viterbi decode, one block per batch. START=20, STOP=21. First-max argmax.
__global__ __launch_bounds__(64)
void k_viterbi(const float* __restrict__ emis, const int* __restrict__ lengths,
               const float* __restrict__ trans,  // [22][22]
               int* __restrict__ out)
{
  int b = blockIdx.x;
  int j = threadIdx.x;
  __shared__ float tr[NTAG*NTAG];
  __shared__ float part[NTAG];
  __shared__ unsigned char bp[(S_LEN-1)*NTAG];
  for (int i = j; i < NTAG*NTAG; i += 64) tr[i] = trans[i];
  int len = lengths[b];
  const float* eb = emis + (size_t)b*S_LEN*NTAG;
  __syncthreads();
  if (j < NTAG) part[j] = eb[j] + tr[(NTAG-2)*NTAG + j];
  __syncthreads();
  for (int t = 1; t < S_LEN; ++t){
    float best = -3.4e38f; int bi = 0;
    if (j < NTAG){
      float e = eb[t*NTAG + j];
      for (int i = 0; i < NTAG; ++i){
        float v = part[i] + tr[i*NTAG + j] + e;
        if (v > best){ best = v; bi = i; }
      }
    }
    __syncthreads();
    if (j < NTAG){
      if (t < len){ part[j] = best; bp[(t-1)*NTAG + j] = (unsigned char)bi; }
      else        { bp[(t-1)*NTAG + j] = (unsigned char)j; }
    }
    __syncthreads();
  }
  if (j == 0){
    float best = -3.4e38f; int tag = 0;
    for (int i = 0; i < NTAG; ++i){
      float v = part[i] + tr[i*NTAG + (NTAG-1)];
      if (v > best){ best = v; tag = i; }
    }
    out[b*S_LEN + S_LEN-1] = (S_LEN-1 < len) ? tag : 0;
    for (int t = S_LEN-2; t >= 0; --t){
      tag = bp[t*NTAG + tag];
      out[b*S_LEN + t] = (t < len) ? tag : 0;
    }
  }
}

// ---------------------------------------------------------------------------
extern "C" void kernel_launch(void* const* d_in, const int* in_sizes, int n_in,
                              void* d_out, int out_size, void* d_ws, size_t ws_size,
                              hipStream_t stream)
{
  (void)in_sizes; (void)n_in; (void)out_size; (void)ws_size;
  const int* char_inputs  = (const int*)d_in[0];
  const int* lengths      = (const int*)d_in[1];
  // d_in[2] = mask (recomputed from lengths)
  const int* gaz_ids      = (const int*)d_in[3];
  const int* gaz_mask     = (const int*)d_in[4];
  const int* rev_gaz_ids  = (const int*)d_in[5];
  const int* rev_gaz_mask = (const int*)d_in[6];
  const void* char_table  = d_in[7];
  const void* gaz_table   = d_in[8];
  const void* w_ih_f = d_in[9];
  const void* w_hh_f = d_in[10];
  const void* b_f    = d_in[11];
  const void* w_ih_b = d_in[12];
  const void* w_hh_b = d_in[13];
  const void* b_b    = d_in[14];
  const void* W_out  = d_in[15];
  const void* b_out  = d_in[16];
  const void* trans  = d_in[17];

  char* ws = (char*)d_ws;
  size_t off = 0;
  auto alloc = [&](size_t bytes)->char*{
    char* p = ws + off; off = (off + bytes + 255) & ~(size_t)255; return p;
  };
  int*   flag   = (int*)  alloc(256);
  float* whh32  = (float*)alloc(2ull*2048*512*4);   //  8.4 MB
  float* wih32  = (float*)alloc(2ull*2048*256*4);   //  4.2 MB
  float* bias32 = (float*)alloc(2ull*2048*4);
  float* wout32 = (float*)alloc(1024ull*22*4);
  float* bout32 = (float*)alloc(22ull*4);
  float* trans32= (float*)alloc(484ull*4);
  float* fwd_in = (float*)alloc(12800ull*256*4);    // 13.1 MB  [S][B][256]
  float* bwd_in = (float*)alloc(12800ull*256*4);    // 13.1 MB
  float* gxc    = (float*)alloc(2ull*2048*MC*4);    // 26.2 MB  (chunk, reused)
  float* hbuf   = (float*)alloc(2ull*2*512*64*4);   //  0.5 MB
  float* cbuf   = (float*)alloc(2ull*512*64*4);     //  0.26 MB
  float* hseq   = (float*)alloc(2ull*200*512*64*4); // 52.4 MB
  float* emis   = (float*)alloc(12800ull*22*4);     //  1.1 MB
  // total ~119.5 MB

  k_detect<<<1,256,0,stream>>>((const u32*)char_table, flag);
  k_cvt_f<<<4096,256,0,stream>>>(w_hh_f, whh32,           1048576, flag);
  k_cvt_f<<<4096,256,0,stream>>>(w_hh_b, whh32 + 1048576, 1048576, flag);
  k_cvt_f<<<2048,256,0,stream>>>(w_ih_f, wih32,            524288, flag);
  k_cvt_f<<<2048,256,0,stream>>>(w_ih_b, wih32 + 524288,   524288, flag);
  k_cvt_f<<<8,256,0,stream>>>(b_f, bias32,        2048, flag);
  k_cvt_f<<<8,256,0,stream>>>(b_b, bias32 + 2048, 2048, flag);
  k_cvt_f<<<88,256,0,stream>>>(W_out, wout32, 22528, flag);
  k_cvt_f<<<1,256,0,stream>>>(b_out, bout32, 22, flag);
  k_cvt_f<<<2,256,0,stream>>>(trans, trans32, 484, flag);

  k_build<<<12800,128,0,stream>>>(char_inputs, lengths, gaz_ids, gaz_mask,
                                  rev_gaz_ids, rev_gaz_mask, char_table, gaz_table,
                                  flag, fwd_in, bwd_in);

  // zero h0/c0 (hbuf and cbuf are contiguous in ws)
  k_zero<<<768,256,0,stream>>>(hbuf, 2*2*512*64 + 2*512*64);

  for (int t0 = 0; t0 < S_LEN; t0 += TCH){
    k_gemm_ih<<<dim3(32,TCH*64/64,2),256,0,stream>>>(fwd_in, bwd_in, wih32, bias32,
                                                     gxc, t0);
    for (int tc = 0; tc < TCH; ++tc)
      k_step<<<dim3(128,2),256,0,stream>>>(whh32, gxc, hbuf, cbuf, hseq, t0+tc, tc);
  }

  k_outproj<<<12800,64,0,stream>>>(hseq, lengths, wout32, bout32, emis);
  k_viterbi<<<64,64,0,stream>>>(emis, lengths, trans32, (int*)d_out);
}